// Round 1
// baseline (3020.077 us; speedup 1.0000x reference)
//
#include <hip/hip_runtime.h>

#define NBATCH 8
#define CIN    256
#define CQ     64
#define HW     4096
#define TI     64
#define TJ     64
#define LDV    68   // padded row stride (floats): 68*4B = 272B = 17*16B -> 16B aligned rows, banks spread by 4/row

// ---------------- Kernel 1: query[n][o][p] = sum_c w[o][c] * src[n][c][p] ----------------
// grid 256 = 8 n * 16 ptiles * 2 ogroups, block 256 (one p per thread, 32 o per block)
__global__ __launch_bounds__(256) void k_query(
    const float* __restrict__ src, const float* __restrict__ w, float* __restrict__ q)
{
    __shared__ float ws[CIN][36];   // ws[c][oo], padded stride 36 (144B, 16B aligned)
    const int bid = blockIdx.x;
    const int n   = bid >> 5;
    const int pt  = (bid >> 1) & 15;
    const int og  = bid & 1;
    const int tid = threadIdx.x;
    // stage w transposed
    for (int r = 0; r < 32; ++r) {
        int idx = r * 256 + tid;           // 0..8191
        int oo = idx >> 8, c = idx & 255;
        ws[c][oo] = w[(og * 32 + oo) * CIN + c];
    }
    __syncthreads();
    const int p = pt * 256 + tid;
    const float* srcn = src + (size_t)n * CIN * HW + p;
    float acc[32];
#pragma unroll
    for (int oo = 0; oo < 32; ++oo) acc[oo] = 0.f;
#pragma unroll 4
    for (int c = 0; c < CIN; ++c) {
        float xv = srcn[(size_t)c * HW];
#pragma unroll
        for (int g = 0; g < 8; ++g) {
            float4 w4 = *(const float4*)&ws[c][g * 4];
            acc[g * 4 + 0] = fmaf(w4.x, xv, acc[g * 4 + 0]);
            acc[g * 4 + 1] = fmaf(w4.y, xv, acc[g * 4 + 1]);
            acc[g * 4 + 2] = fmaf(w4.z, xv, acc[g * 4 + 2]);
            acc[g * 4 + 3] = fmaf(w4.w, xv, acc[g * 4 + 3]);
        }
    }
    float* qn = q + ((size_t)n * CQ + og * 32) * HW + p;
#pragma unroll
    for (int oo = 0; oo < 32; ++oo) qn[(size_t)oo * HW] = acc[oo];
}

// ---------------- Kernel 2: row stats m_i = max_j s_ij, l_i = sum_j exp(s_ij - m_i) ----------------
// grid 512 = 8 n * 64 itiles, block 256 (tx = j-dim 16, ty = i-dim 16, 4x4 register tile)
__global__ __launch_bounds__(256) void k_stats(
    const float* __restrict__ q, float* __restrict__ mrow, float* __restrict__ lrow)
{
    __shared__ float Qi[CQ][LDV];
    __shared__ float Qj[CQ][LDV];
    const int bid = blockIdx.x;
    const int n   = bid >> 6;
    const int i0  = (bid & 63) * TI;
    const int tid = threadIdx.x;
    const int tx = tid & 15, ty = tid >> 4;
    const float* qn = q + (size_t)n * CQ * HW;
#pragma unroll
    for (int r = 0; r < 4; ++r) {
        int idx4 = (r * 256 + tid) * 4;
        int c = idx4 >> 6, col = idx4 & 63;
        *(float4*)&Qi[c][col] = *(const float4*)&qn[(size_t)c * HW + i0 + col];
    }
    float m_run[4], l_run[4];
#pragma unroll
    for (int ii = 0; ii < 4; ++ii) { m_run[ii] = -1e30f; l_run[ii] = 0.f; }

    for (int jt = 0; jt < HW / TJ; ++jt) {
        const int j0 = jt * TJ;
        __syncthreads();
#pragma unroll
        for (int r = 0; r < 4; ++r) {
            int idx4 = (r * 256 + tid) * 4;
            int c = idx4 >> 6, col = idx4 & 63;
            *(float4*)&Qj[c][col] = *(const float4*)&qn[(size_t)c * HW + j0 + col];
        }
        __syncthreads();
        float s[4][4];
#pragma unroll
        for (int a = 0; a < 4; ++a)
#pragma unroll
            for (int b = 0; b < 4; ++b) s[a][b] = 0.f;
#pragma unroll 8
        for (int c = 0; c < CQ; ++c) {
            float4 a4 = *(const float4*)&Qi[c][ty * 4];
            float4 b4 = *(const float4*)&Qj[c][tx * 4];
            float av[4] = {a4.x, a4.y, a4.z, a4.w};
            float bv[4] = {b4.x, b4.y, b4.z, b4.w};
#pragma unroll
            for (int a = 0; a < 4; ++a)
#pragma unroll
                for (int b = 0; b < 4; ++b)
                    s[a][b] = fmaf(av[a], bv[b], s[a][b]);
        }
#pragma unroll
        for (int ii = 0; ii < 4; ++ii) {
            float tmax = fmaxf(fmaxf(s[ii][0], s[ii][1]), fmaxf(s[ii][2], s[ii][3]));
#pragma unroll
            for (int off = 1; off < 16; off <<= 1)
                tmax = fmaxf(tmax, __shfl_xor(tmax, off));
            float mn = fmaxf(m_run[ii], tmax);
            float ps = __expf(s[ii][0] - mn) + __expf(s[ii][1] - mn)
                     + __expf(s[ii][2] - mn) + __expf(s[ii][3] - mn);
#pragma unroll
            for (int off = 1; off < 16; off <<= 1)
                ps += __shfl_xor(ps, off);
            l_run[ii] = l_run[ii] * __expf(m_run[ii] - mn) + ps;
            m_run[ii] = mn;
        }
    }
    if (tx == 0) {
#pragma unroll
        for (int ii = 0; ii < 4; ++ii) {
            int i = i0 + ty * 4 + ii;
            mrow[n * HW + i] = m_run[ii];
            lrow[n * HW + i] = l_run[ii];
        }
    }
}

// ---------------- Kernel 3: apply attention ----------------
// grid 1024: bid = (n*2 + chunk)*64 + itile. chunk 0: ref (blend epilogue, out ch 0..255),
// chunk 1: src (out ch 256..511). Per j-tile: recompute S, P=exp(s-m)/l into LDS,
// then PV GEMM streaming V through a 64-channel LDS slab (union with Qj buffer).
__global__ __launch_bounds__(256) void k_apply(
    const float* __restrict__ q, const float* __restrict__ srcf,
    const float* __restrict__ reff, const float* __restrict__ mask,
    const float* __restrict__ mrow, const float* __restrict__ lrow,
    float* __restrict__ out)
{
    __shared__ float Qi[CQ][LDV];      // 17.4 KB
    __shared__ float P[TI][LDV];       // 17.4 KB
    __shared__ float U[CQ * LDV];      // 17.4 KB union: Qj tile / V slab
    const int bid   = blockIdx.x;
    const int itile = bid & 63;
    const int chunk = (bid >> 6) & 1;
    const int n     = bid >> 7;
    const int i0    = itile * TI;
    const int tid   = threadIdx.x;
    const int tx = tid & 15, ty = tid >> 4;
    const float* qn = q + (size_t)n * CQ * HW;
    const float* V  = (chunk == 0 ? reff : srcf) + (size_t)n * CIN * HW;
#pragma unroll
    for (int r = 0; r < 4; ++r) {
        int idx4 = (r * 256 + tid) * 4;
        int c = idx4 >> 6, col = idx4 & 63;
        *(float4*)&Qi[c][col] = *(const float4*)&qn[(size_t)c * HW + i0 + col];
    }
    float mi[4], invl[4];
#pragma unroll
    for (int ii = 0; ii < 4; ++ii) {
        int i = i0 + ty * 4 + ii;
        mi[ii] = mrow[n * HW + i];
        invl[ii] = 1.0f / lrow[n * HW + i];
    }
    float acc[4][4][4];   // [slab][cc][ii]; channel = sl*64 + cc*16 + tx, i = i0 + ty*4 + ii
#pragma unroll
    for (int a = 0; a < 4; ++a)
#pragma unroll
        for (int b = 0; b < 4; ++b)
#pragma unroll
            for (int d = 0; d < 4; ++d) acc[a][b][d] = 0.f;

    for (int jt = 0; jt < HW / TJ; ++jt) {
        const int j0 = jt * TJ;
        __syncthreads();   // prev iteration's PV reads of U and P are done
#pragma unroll
        for (int r = 0; r < 4; ++r) {
            int idx4 = (r * 256 + tid) * 4;
            int c = idx4 >> 6, col = idx4 & 63;
            *(float4*)&U[c * LDV + col] = *(const float4*)&qn[(size_t)c * HW + j0 + col];
        }
        __syncthreads();
        float s[4][4];
#pragma unroll
        for (int a = 0; a < 4; ++a)
#pragma unroll
            for (int b = 0; b < 4; ++b) s[a][b] = 0.f;
#pragma unroll 8
        for (int c = 0; c < CQ; ++c) {
            float4 a4 = *(const float4*)&Qi[c][ty * 4];
            float4 b4 = *(const float4*)&U[c * LDV + tx * 4];
            float av[4] = {a4.x, a4.y, a4.z, a4.w};
            float bv[4] = {b4.x, b4.y, b4.z, b4.w};
#pragma unroll
            for (int a = 0; a < 4; ++a)
#pragma unroll
                for (int b = 0; b < 4; ++b)
                    s[a][b] = fmaf(av[a], bv[b], s[a][b]);
        }
#pragma unroll
        for (int ii = 0; ii < 4; ++ii) {
            float4 pw;
            pw.x = __expf(s[ii][0] - mi[ii]) * invl[ii];
            pw.y = __expf(s[ii][1] - mi[ii]) * invl[ii];
            pw.z = __expf(s[ii][2] - mi[ii]) * invl[ii];
            pw.w = __expf(s[ii][3] - mi[ii]) * invl[ii];
            *(float4*)&P[ty * 4 + ii][tx * 4] = pw;
        }
#pragma unroll
        for (int sl = 0; sl < 4; ++sl) {
            __syncthreads();   // S-compute reads of U done (sl=0) / prev slab PV done; P visible
#pragma unroll
            for (int r = 0; r < 4; ++r) {
                int idx4 = (r * 256 + tid) * 4;
                int cl = idx4 >> 6, j = idx4 & 63;
                *(float4*)&U[cl * LDV + j] =
                    *(const float4*)&V[(size_t)(sl * 64 + cl) * HW + j0 + j];
            }
            __syncthreads();
#pragma unroll 4
            for (int js = 0; js < TJ; js += 4) {
                float4 p4[4], v4[4];
#pragma unroll
                for (int ii = 0; ii < 4; ++ii)
                    p4[ii] = *(const float4*)&P[ty * 4 + ii][js];
#pragma unroll
                for (int cc = 0; cc < 4; ++cc)
                    v4[cc] = *(const float4*)&U[(cc * 16 + tx) * LDV + js];
#pragma unroll
                for (int cc = 0; cc < 4; ++cc)
#pragma unroll
                    for (int ii = 0; ii < 4; ++ii) {
                        acc[sl][cc][ii] = fmaf(v4[cc].x, p4[ii].x, acc[sl][cc][ii]);
                        acc[sl][cc][ii] = fmaf(v4[cc].y, p4[ii].y, acc[sl][cc][ii]);
                        acc[sl][cc][ii] = fmaf(v4[cc].z, p4[ii].z, acc[sl][cc][ii]);
                        acc[sl][cc][ii] = fmaf(v4[cc].w, p4[ii].w, acc[sl][cc][ii]);
                    }
            }
        }
    }
    // epilogue
    const int iBase = i0 + ty * 4;
    float4 m4 = {0.f, 0.f, 0.f, 0.f};
    if (chunk == 0) m4 = *(const float4*)&mask[n * HW + iBase];
#pragma unroll
    for (int sl = 0; sl < 4; ++sl)
#pragma unroll
        for (int cc = 0; cc < 4; ++cc) {
            int ch = sl * 64 + cc * 16 + tx;
            float4 o4;
            o4.x = acc[sl][cc][0];
            o4.y = acc[sl][cc][1];
            o4.z = acc[sl][cc][2];
            o4.w = acc[sl][cc][3];
            if (chunk == 0) {
                float4 r4 = *(const float4*)&V[(size_t)ch * HW + iBase];
                o4.x = (1.f - m4.x) * o4.x + m4.x * r4.x;
                o4.y = (1.f - m4.y) * o4.y + m4.y * r4.y;
                o4.z = (1.f - m4.z) * o4.z + m4.z * r4.z;
                o4.w = (1.f - m4.w) * o4.w + m4.w * r4.w;
                *(float4*)&out[((size_t)n * 2 * CIN + ch) * HW + iBase] = o4;
            } else {
                *(float4*)&out[((size_t)n * 2 * CIN + CIN + ch) * HW + iBase] = o4;
            }
        }
}

extern "C" void kernel_launch(void* const* d_in, const int* in_sizes, int n_in,
                              void* d_out, int out_size, void* d_ws, size_t ws_size,
                              hipStream_t stream) {
    const float* src_mask = (const float*)d_in[0];
    const float* src_feat = (const float*)d_in[1];
    const float* ref_feat = (const float*)d_in[2];
    const float* conv_w   = (const float*)d_in[3];
    float* out = (float*)d_out;

    float* qbuf = (float*)d_ws;                               // 8 MB: [8][64][4096]
    float* mrow = qbuf + (size_t)NBATCH * CQ * HW;            // 128 KB
    float* lrow = mrow + (size_t)NBATCH * HW;                 // 128 KB

    k_query<<<dim3(256), dim3(256), 0, stream>>>(src_feat, conv_w, qbuf);
    k_stats<<<dim3(512), dim3(256), 0, stream>>>(qbuf, mrow, lrow);
    k_apply<<<dim3(1024), dim3(256), 0, stream>>>(qbuf, src_feat, ref_feat, src_mask,
                                                  mrow, lrow, out);
}

// Round 2
// 1414.590 us; speedup vs baseline: 2.1349x; 2.1349x over previous
//
#include <hip/hip_runtime.h>

#define NBATCH 8
#define CIN    256
#define CQ     64
#define HW     4096

typedef __attribute__((ext_vector_type(8))) __bf16 bf16x8;
typedef __attribute__((ext_vector_type(4))) float  f32x4;

#define MFMA16(a,b,c) __builtin_amdgcn_mfma_f32_16x16x32_bf16((a),(b),(c),0,0,0)

__device__ __forceinline__ unsigned short f2bf(float f) {
    unsigned u = __float_as_uint(f);
    u += 0x7fffu + ((u >> 16) & 1u);            // round-to-nearest-even
    return (unsigned short)(u >> 16);
}
__device__ __forceinline__ float bf2f(unsigned short h) {
    return __uint_as_float((unsigned)h << 16);
}

// ---------------- k_prep: V (ref, src) fp32 -> bf16 hi/lo, layout [t][n][c][p], t0=ref ----
__global__ __launch_bounds__(256) void k_prep(
    const float* __restrict__ reff, const float* __restrict__ srcf,
    unsigned short* __restrict__ vh, unsigned short* __restrict__ vl, int vsplit)
{
    const size_t half = (size_t)NBATCH * CIN * HW;
    const size_t i4 = ((size_t)blockIdx.x * 256 + threadIdx.x) * 4;
    float4 v = (i4 < half) ? *(const float4*)(reff + i4)
                           : *(const float4*)(srcf + (i4 - half));
    unsigned short h0 = f2bf(v.x), h1 = f2bf(v.y), h2 = f2bf(v.z), h3 = f2bf(v.w);
    uint2 uh;
    uh.x = (unsigned)h0 | ((unsigned)h1 << 16);
    uh.y = (unsigned)h2 | ((unsigned)h3 << 16);
    *(uint2*)(vh + i4) = uh;
    if (vsplit) {
        unsigned short l0 = f2bf(v.x - bf2f(h0)), l1 = f2bf(v.y - bf2f(h1));
        unsigned short l2 = f2bf(v.z - bf2f(h2)), l3 = f2bf(v.w - bf2f(h3));
        uint2 ul;
        ul.x = (unsigned)l0 | ((unsigned)l1 << 16);
        ul.y = (unsigned)l2 | ((unsigned)l3 << 16);
        *(uint2*)(vl + i4) = ul;
    }
}

// ---------------- k_query: q[n][o][p] then store TRANSPOSED qt[n][p][c] as bf16 hi/lo ----
__global__ __launch_bounds__(256) void k_query(
    const float* __restrict__ src, const float* __restrict__ w,
    unsigned short* __restrict__ qth, unsigned short* __restrict__ qtl)
{
    __shared__ float ws[CIN][36];
    const int bid = blockIdx.x;
    const int n  = bid >> 5;
    const int pt = (bid >> 1) & 15;
    const int og = bid & 1;
    const int tid = threadIdx.x;
    for (int r = 0; r < 32; ++r) {
        int idx = r * 256 + tid;
        int oo = idx >> 8, c = idx & 255;
        ws[c][oo] = w[(og * 32 + oo) * CIN + c];
    }
    __syncthreads();
    const int p = pt * 256 + tid;
    const float* srcn = src + (size_t)n * CIN * HW + p;
    float acc[32];
#pragma unroll
    for (int oo = 0; oo < 32; ++oo) acc[oo] = 0.f;
#pragma unroll 4
    for (int c = 0; c < CIN; ++c) {
        float xv = srcn[(size_t)c * HW];
#pragma unroll
        for (int gg = 0; gg < 8; ++gg) {
            float4 w4 = *(const float4*)&ws[c][gg * 4];
            acc[gg * 4 + 0] = fmaf(w4.x, xv, acc[gg * 4 + 0]);
            acc[gg * 4 + 1] = fmaf(w4.y, xv, acc[gg * 4 + 1]);
            acc[gg * 4 + 2] = fmaf(w4.z, xv, acc[gg * 4 + 2]);
            acc[gg * 4 + 3] = fmaf(w4.w, xv, acc[gg * 4 + 3]);
        }
    }
    const size_t base = ((size_t)n * HW + p) * CQ + og * 32;   // even element index
    unsigned int* ph = (unsigned int*)(qth + base);
    unsigned int* pl = (unsigned int*)(qtl + base);
#pragma unroll
    for (int k = 0; k < 16; ++k) {
        unsigned short h0 = f2bf(acc[2 * k]),     h1 = f2bf(acc[2 * k + 1]);
        unsigned short l0 = f2bf(acc[2 * k] - bf2f(h0));
        unsigned short l1 = f2bf(acc[2 * k + 1] - bf2f(h1));
        ph[k] = (unsigned)h0 | ((unsigned)h1 << 16);
        pl[k] = (unsigned)l0 | ((unsigned)l1 << 16);
    }
}

// ---------------- k_stats: online row max / sumexp via split-bf16 MFMA ----------------
// grid 512 = 8n * 64 itiles; block 256 = 4 waves; wave w owns i-cols i0+w*16..+16.
__global__ __launch_bounds__(256) void k_stats(
    const unsigned short* __restrict__ qh, const unsigned short* __restrict__ ql,
    float* __restrict__ mrow, float* __restrict__ lrow)
{
    const int bid = blockIdx.x;
    const int n = bid >> 6;
    const int i0 = (bid & 63) * 64;
    const int tid = threadIdx.x;
    const int lane = tid & 63;
    const int wv = tid >> 6;
    const int r16 = lane & 15;
    const int g = lane >> 4;
    const unsigned short* qhn = qh + (size_t)n * HW * CQ;
    const unsigned short* qln = ql + (size_t)n * HW * CQ;
    const int irow = i0 + wv * 16 + r16;
    bf16x8 bh[2], bl[2];
#pragma unroll
    for (int ks = 0; ks < 2; ++ks) {
        bh[ks] = *(const bf16x8*)(qhn + (size_t)irow * CQ + ks * 32 + g * 8);
        bl[ks] = *(const bf16x8*)(qln + (size_t)irow * CQ + ks * 32 + g * 8);
    }
    float m_run = -1e30f, l_run = 0.f;
#pragma unroll 1
    for (int jt = 0; jt < HW / 64; ++jt) {
        const int j0 = jt * 64;
        f32x4 sacc[4];
#pragma unroll
        for (int jf = 0; jf < 4; ++jf) {
            const int jrow = j0 + jf * 16 + r16;
            bf16x8 ah0 = *(const bf16x8*)(qhn + (size_t)jrow * CQ + g * 8);
            bf16x8 ah1 = *(const bf16x8*)(qhn + (size_t)jrow * CQ + 32 + g * 8);
            bf16x8 al0 = *(const bf16x8*)(qln + (size_t)jrow * CQ + g * 8);
            bf16x8 al1 = *(const bf16x8*)(qln + (size_t)jrow * CQ + 32 + g * 8);
            f32x4 s = {0.f, 0.f, 0.f, 0.f};
            s = MFMA16(ah0, bh[0], s);
            s = MFMA16(ah0, bl[0], s);
            s = MFMA16(al0, bh[0], s);
            s = MFMA16(ah1, bh[1], s);
            s = MFMA16(ah1, bl[1], s);
            s = MFMA16(al1, bh[1], s);
            sacc[jf] = s;
        }
        float tmax = -1e30f;
#pragma unroll
        for (int jf = 0; jf < 4; ++jf)
#pragma unroll
            for (int r = 0; r < 4; ++r) tmax = fmaxf(tmax, sacc[jf][r]);
        tmax = fmaxf(tmax, __shfl_xor(tmax, 16));
        tmax = fmaxf(tmax, __shfl_xor(tmax, 32));
        const float mn = fmaxf(m_run, tmax);
        float ps = 0.f;
#pragma unroll
        for (int jf = 0; jf < 4; ++jf)
#pragma unroll
            for (int r = 0; r < 4; ++r) ps += __expf(sacc[jf][r] - mn);
        ps += __shfl_xor(ps, 16);
        ps += __shfl_xor(ps, 32);
        l_run = l_run * __expf(m_run - mn) + ps;
        m_run = mn;
    }
    if (g == 0) {
        mrow[n * HW + irow] = m_run;
        lrow[n * HW + irow] = l_run;
    }
}

// ---------------- k_apply: recompute S^T tile -> P -> LDS -> PV MFMA ----------------
// grid 1024: bid = (n*2+chunk)*64 + itile. chunk0: ref/blend (out ch 0..255), chunk1: src.
// wave w: S-phase j-strip w*16..+16 of the 64x64 tile; PV-phase channels w*64..+64.
template<int VSPLIT>
__global__ __launch_bounds__(256) void k_apply(
    const unsigned short* __restrict__ qh, const unsigned short* __restrict__ ql,
    const unsigned short* __restrict__ vhp, const unsigned short* __restrict__ vlp,
    const float* __restrict__ reff, const float* __restrict__ maskp,
    const float* __restrict__ mrow, const float* __restrict__ lrow,
    float* __restrict__ out)
{
    __shared__ __align__(16) unsigned char P2h[64 * 128];  // P[i][j] bf16, XOR-swizzled
    __shared__ __align__(16) unsigned char P2l[64 * 128];
    const int bid = blockIdx.x;
    const int itile = bid & 63;
    const int chunk = (bid >> 6) & 1;
    const int n     = bid >> 7;
    const int i0 = itile * 64;
    const int tid = threadIdx.x;
    const int lane = tid & 63;
    const int wv = tid >> 6;
    const int r16 = lane & 15;
    const int g = lane >> 4;

    const unsigned short* qhn = qh + (size_t)n * HW * CQ;
    const unsigned short* qln = ql + (size_t)n * HW * CQ;
    const unsigned short* Vh = vhp + ((size_t)chunk * NBATCH + n) * CIN * HW;
    const unsigned short* Vl = vlp + ((size_t)chunk * NBATCH + n) * CIN * HW;

    // persistent B-frags for S^T (the i-side of the tile)
    bf16x8 qbh[4][2], qbl[4][2];
#pragma unroll
    for (int f = 0; f < 4; ++f) {
        const int irow = i0 + f * 16 + r16;
#pragma unroll
        for (int ks = 0; ks < 2; ++ks) {
            qbh[f][ks] = *(const bf16x8*)(qhn + (size_t)irow * CQ + ks * 32 + g * 8);
            qbl[f][ks] = *(const bf16x8*)(qln + (size_t)irow * CQ + ks * 32 + g * 8);
        }
    }
    float mi[4], il[4];
#pragma unroll
    for (int f = 0; f < 4; ++f) {
        const int i = i0 + f * 16 + r16;
        mi[f] = mrow[n * HW + i];
        il[f] = 1.0f / lrow[n * HW + i];
    }
    f32x4 acc[4][4];
#pragma unroll
    for (int a = 0; a < 4; ++a)
#pragma unroll
        for (int b = 0; b < 4; ++b) acc[a][b] = (f32x4){0.f, 0.f, 0.f, 0.f};

    const int c0 = wv * 64;
#pragma unroll 1
    for (int jt = 0; jt < HW / 64; ++jt) {
        const int j0 = jt * 64;
        // ---- S^T strip: rows j0+wv*16..+16, cols i0..i0+64 (registers + global only)
        const int jrow = j0 + wv * 16 + r16;
        bf16x8 ah[2], al[2];
#pragma unroll
        for (int ks = 0; ks < 2; ++ks) {
            ah[ks] = *(const bf16x8*)(qhn + (size_t)jrow * CQ + ks * 32 + g * 8);
            al[ks] = *(const bf16x8*)(qln + (size_t)jrow * CQ + ks * 32 + g * 8);
        }
        f32x4 sv[4];
#pragma unroll
        for (int f = 0; f < 4; ++f) {
            f32x4 s = {0.f, 0.f, 0.f, 0.f};
#pragma unroll
            for (int ks = 0; ks < 2; ++ks) {
                s = MFMA16(ah[ks], qbh[f][ks], s);
                s = MFMA16(ah[ks], qbl[f][ks], s);
                s = MFMA16(al[ks], qbh[f][ks], s);
            }
            sv[f] = s;
        }
        __syncthreads();   // previous iteration's PV reads of P2 are done
        // ---- softmax + pack: lane holds 4 consecutive j for col i
#pragma unroll
        for (int f = 0; f < 4; ++f) {
            unsigned short ph[4], pl[4];
#pragma unroll
            for (int r = 0; r < 4; ++r) {
                const float p = __expf(sv[f][r] - mi[f]) * il[f];
                ph[r] = f2bf(p);
                pl[r] = f2bf(p - bf2f(ph[r]));
            }
            const int iloc = f * 16 + r16;
            const int jb = (wv * 16 + g * 4) * 2;
            const int off = iloc * 128 + (jb ^ ((iloc & 7) << 4));
            uint2 uh, ul;
            uh.x = (unsigned)ph[0] | ((unsigned)ph[1] << 16);
            uh.y = (unsigned)ph[2] | ((unsigned)ph[3] << 16);
            ul.x = (unsigned)pl[0] | ((unsigned)pl[1] << 16);
            ul.y = (unsigned)pl[2] | ((unsigned)pl[3] << 16);
            *(uint2*)(P2h + off) = uh;
            *(uint2*)(P2l + off) = ul;
        }
        __syncthreads();   // P2 visible to all waves
        // ---- PV: out[c,i] += V[c,j] * P[i,j]
#pragma unroll
        for (int ks = 0; ks < 2; ++ks) {
            bf16x8 pbh[4], pbl[4];
#pragma unroll
            for (int f = 0; f < 4; ++f) {
                const int iloc = f * 16 + r16;
                const int jb = ks * 64 + g * 16;
                const int off = iloc * 128 + (jb ^ ((iloc & 7) << 4));
                pbh[f] = *(const bf16x8*)(P2h + off);
                pbl[f] = *(const bf16x8*)(P2l + off);
            }
#pragma unroll
            for (int cf = 0; cf < 4; ++cf) {
                const int crow = c0 + cf * 16 + r16;
                const size_t voff = (size_t)crow * HW + j0 + ks * 32 + g * 8;
                const bf16x8 va = *(const bf16x8*)(Vh + voff);
                const bf16x8 vbl = VSPLIT ? *(const bf16x8*)(Vl + voff) : va;
#pragma unroll
                for (int f = 0; f < 4; ++f) {
                    acc[cf][f] = MFMA16(va, pbh[f], acc[cf][f]);
                    acc[cf][f] = MFMA16(va, pbl[f], acc[cf][f]);
                    if (VSPLIT) acc[cf][f] = MFMA16(vbl, pbh[f], acc[cf][f]);
                }
            }
        }
    }
    // ---- epilogue: lane's acc[cf][f][r] -> c = c0+cf*16+g*4+r, i = i0+f*16+r16
    const size_t outbase = ((size_t)n * 2 * CIN + (size_t)chunk * CIN) * HW;
#pragma unroll
    for (int f = 0; f < 4; ++f) {
        const int i = i0 + f * 16 + r16;
        float mk = 0.f;
        if (chunk == 0) mk = maskp[n * HW + i];
#pragma unroll
        for (int cf = 0; cf < 4; ++cf) {
#pragma unroll
            for (int r = 0; r < 4; ++r) {
                const int c = c0 + cf * 16 + g * 4 + r;
                float o = acc[cf][f][r];
                if (chunk == 0) {
                    const float rv = reff[((size_t)n * CIN + c) * HW + i];
                    o = (1.f - mk) * o + mk * rv;
                }
                out[outbase + (size_t)c * HW + i] = o;
            }
        }
    }
}

extern "C" void kernel_launch(void* const* d_in, const int* in_sizes, int n_in,
                              void* d_out, int out_size, void* d_ws, size_t ws_size,
                              hipStream_t stream) {
    const float* src_mask = (const float*)d_in[0];
    const float* src_feat = (const float*)d_in[1];
    const float* ref_feat = (const float*)d_in[2];
    const float* conv_w   = (const float*)d_in[3];
    float* out = (float*)d_out;

    char* ws = (char*)d_ws;
    const size_t qbytes = (size_t)NBATCH * HW * CQ * sizeof(unsigned short);        // 4 MB
    const size_t sbytes = (size_t)NBATCH * HW * sizeof(float);                      // 128 KB
    const size_t vbytes = (size_t)2 * NBATCH * CIN * HW * sizeof(unsigned short);   // 33.6 MB
    unsigned short* qth = (unsigned short*)ws;  ws += qbytes;
    unsigned short* qtl = (unsigned short*)ws;  ws += qbytes;
    float* mrow = (float*)ws;                   ws += sbytes;
    float* lrow = (float*)ws;                   ws += sbytes;
    unsigned short* vh = (unsigned short*)ws;   ws += vbytes;
    const size_t used = (size_t)(ws - (char*)d_ws);
    const int vsplit = (ws_size >= used + vbytes) ? 1 : 0;
    unsigned short* vl = vsplit ? (unsigned short*)ws : vh;

    k_prep<<<dim3(16384), dim3(256), 0, stream>>>(ref_feat, src_feat, vh, vl, vsplit);
    k_query<<<dim3(256), dim3(256), 0, stream>>>(src_feat, conv_w, qth, qtl);
    k_stats<<<dim3(512), dim3(256), 0, stream>>>(qth, qtl, mrow, lrow);
    if (vsplit)
        k_apply<1><<<dim3(1024), dim3(256), 0, stream>>>(qth, qtl, vh, vl, ref_feat,
                                                         src_mask, mrow, lrow, out);
    else
        k_apply<0><<<dim3(1024), dim3(256), 0, stream>>>(qth, qtl, vh, vl, ref_feat,
                                                         src_mask, mrow, lrow, out);
}

// Round 3
// 656.300 us; speedup vs baseline: 4.6017x; 2.1554x over previous
//
#include <hip/hip_runtime.h>

#define NBATCH 8
#define CIN    256
#define CQ     64
#define HW     4096
#define NT     (HW / 64)

typedef __attribute__((ext_vector_type(8))) _Float16 f16x8;
typedef __attribute__((ext_vector_type(4))) _Float16 f16x4;
typedef __attribute__((ext_vector_type(4))) float    f32x4;
typedef _Float16 half_t;

#define MFMA_F16(a, b, c) __builtin_amdgcn_mfma_f32_16x16x32_f16((a), (b), (c), 0, 0, 0)

// ---------------- k_prep: V (ref, src) fp32 -> fp16, layout [t][n][c][p], t0=ref ----------
__global__ __launch_bounds__(256) void k_prep(
    const float* __restrict__ reff, const float* __restrict__ srcf,
    half_t* __restrict__ vh)
{
    const size_t half_n = (size_t)NBATCH * CIN * HW;
    const size_t i4 = ((size_t)blockIdx.x * 256 + threadIdx.x) * 4;
    float4 v = (i4 < half_n) ? *(const float4*)(reff + i4)
                             : *(const float4*)(srcf + (i4 - half_n));
    f16x4 h;
    h[0] = (half_t)v.x; h[1] = (half_t)v.y; h[2] = (half_t)v.z; h[3] = (half_t)v.w;
    *(f16x4*)(vh + i4) = h;
}

// ---------------- k_query: q = conv1x1(src), store transposed qt[n][p][c] fp16 hi/lo ------
__global__ __launch_bounds__(256) void k_query(
    const float* __restrict__ src, const float* __restrict__ w,
    half_t* __restrict__ qth, half_t* __restrict__ qtl)
{
    __shared__ float ws[CIN][36];
    const int bid = blockIdx.x;
    const int n  = bid >> 5;
    const int pt = (bid >> 1) & 15;
    const int og = bid & 1;
    const int tid = threadIdx.x;
    for (int r = 0; r < 32; ++r) {
        int idx = r * 256 + tid;
        int oo = idx >> 8, c = idx & 255;
        ws[c][oo] = w[(og * 32 + oo) * CIN + c];
    }
    __syncthreads();
    const int p = pt * 256 + tid;
    const float* srcn = src + (size_t)n * CIN * HW + p;
    float acc[32];
#pragma unroll
    for (int oo = 0; oo < 32; ++oo) acc[oo] = 0.f;
#pragma unroll 4
    for (int c = 0; c < CIN; ++c) {
        float xv = srcn[(size_t)c * HW];
#pragma unroll
        for (int gg = 0; gg < 8; ++gg) {
            float4 w4 = *(const float4*)&ws[c][gg * 4];
            acc[gg * 4 + 0] = fmaf(w4.x, xv, acc[gg * 4 + 0]);
            acc[gg * 4 + 1] = fmaf(w4.y, xv, acc[gg * 4 + 1]);
            acc[gg * 4 + 2] = fmaf(w4.z, xv, acc[gg * 4 + 2]);
            acc[gg * 4 + 3] = fmaf(w4.w, xv, acc[gg * 4 + 3]);
        }
    }
    const size_t base = ((size_t)n * HW + p) * CQ + og * 32;
    half_t hb[32], lb[32];
#pragma unroll
    for (int oo = 0; oo < 32; ++oo) {
        hb[oo] = (half_t)acc[oo];
        lb[oo] = (half_t)(acc[oo] - (float)hb[oo]);
    }
#pragma unroll
    for (int v = 0; v < 4; ++v) {
        *(f16x8*)(qth + base + v * 8) = *(f16x8*)&hb[v * 8];
        *(f16x8*)(qtl + base + v * 8) = *(f16x8*)&lb[v * 8];
    }
}

// ---------------- k_apply: fused flash attention (online softmax) + blend + concat -------
// grid 1024: logical = (n*2+chunk)*64 + itile, XCD-swizzled.
// Per j-tile, ONE barrier:
//   phase1: [issue V loads][issue qj(jt+1) loads] S-MFMA from QJ[buf] -> online softmax
//           -> P/FS writes -> stage qj(jt+1) ds_writes -> __syncthreads
//   phase2: rescale acc (rare) -> PV MFMA from P[buf] + V regs
__global__ __launch_bounds__(256, 3) void k_apply(
    const half_t* __restrict__ qh, const half_t* __restrict__ ql,
    const half_t* __restrict__ vhp, const float* __restrict__ reff,
    const float* __restrict__ maskp, float* __restrict__ out)
{
    __shared__ __align__(16) half_t QJ[2][2][64 * 64];  // [buf][hi/lo][row*64 + swz col]
    __shared__ __align__(16) half_t P[2][64 * 64];      // [buf][i*64 + swz j]
    __shared__ float FS[2][64];
    __shared__ float LS[64];

    const int bid = blockIdx.x;
    const int logical = (bid & 7) * 128 + (bid >> 3);   // XCD-contiguous groups
    const int itile = logical & 63;
    const int chunk = (logical >> 6) & 1;
    const int n     = logical >> 7;
    const int i0 = itile * 64;
    const int tid = threadIdx.x;
    const int lane = tid & 63;
    const int wv = tid >> 6;
    const int r16 = lane & 15;
    const int g = lane >> 4;
    const int rl = (lane >> 3) & 7;   // staging row-local
    const int cb = lane & 7;          // staging 16B-chunk index

    const half_t* qhn = qh + (size_t)n * HW * CQ;
    const half_t* qln = ql + (size_t)n * HW * CQ;
    const half_t* V = vhp + ((size_t)chunk * NBATCH + n) * CIN * HW;

    // persistent B-frags (i-side): i = i0 + wv*16 + r16
    const int iq = i0 + wv * 16 + r16;
    f16x8 qbh[2], qbl[2];
#pragma unroll
    for (int ks = 0; ks < 2; ++ks) {
        qbh[ks] = *(const f16x8*)(qhn + (size_t)iq * CQ + ks * 32 + g * 8);
        qbl[ks] = *(const f16x8*)(qln + (size_t)iq * CQ + ks * 32 + g * 8);
    }

    f32x4 acc[4][4];   // [cf][fi]: c = wv*64+cf*16+g*4+r, i = i0+fi*16+r16
#pragma unroll
    for (int a = 0; a < 4; ++a)
#pragma unroll
        for (int b = 0; b < 4; ++b) acc[a][b] = (f32x4){0.f, 0.f, 0.f, 0.f};
    float M_run = -1e30f, l_run = 0.f;
    const int c0 = wv * 64;

    // ---- prologue: stage qj tile 0 into QJ[0]
    {
        f16x8 stg[4];
#pragma unroll
        for (int pl = 0; pl < 2; ++pl) {
            const half_t* s = pl ? qln : qhn;
#pragma unroll
            for (int t = 0; t < 2; ++t)
                stg[pl * 2 + t] = *(const f16x8*)(s + (size_t)(wv * 16 + t * 8 + rl) * CQ + cb * 8);
        }
#pragma unroll
        for (int pl = 0; pl < 2; ++pl)
#pragma unroll
            for (int t = 0; t < 2; ++t) {
                const int row = wv * 16 + t * 8 + rl;
                *(f16x8*)&QJ[0][pl][row * 64 + ((cb * 8) ^ (rl * 8))] = stg[pl * 2 + t];
            }
    }
    __syncthreads();

#pragma unroll 1
    for (int jt = 0; jt < NT; ++jt) {
        const int j0 = jt * 64;
        const int buf = jt & 1;
        const int jn = (jt + 1 < NT) ? (jt + 1) * 64 : 0;

        // ---- phase 1a: issue V loads (consumed in phase2) + qj(jt+1) loads
        f16x8 vfrag[4][2];
#pragma unroll
        for (int cf = 0; cf < 4; ++cf)
#pragma unroll
            for (int ks = 0; ks < 2; ++ks)
                vfrag[cf][ks] = *(const f16x8*)(V + (size_t)(c0 + cf * 16 + r16) * HW
                                                + j0 + ks * 32 + g * 8);
        f16x8 stg[4];
#pragma unroll
        for (int pl = 0; pl < 2; ++pl) {
            const half_t* s = pl ? qln : qhn;
#pragma unroll
            for (int t = 0; t < 2; ++t)
                stg[pl * 2 + t] = *(const f16x8*)(s + (size_t)(jn + wv * 16 + t * 8 + rl) * CQ + cb * 8);
        }

        // ---- phase 1b: S^T strip: rows j (4 subtiles), cols i = wv strip
        f32x4 sv[4];
#pragma unroll
        for (int f = 0; f < 4; ++f) {
            const int row = f * 16 + r16;
            const int sw = (row & 7) * 8;
            f16x8 ah0 = *(const f16x8*)&QJ[buf][0][row * 64 + ((g * 8) ^ sw)];
            f16x8 ah1 = *(const f16x8*)&QJ[buf][0][row * 64 + ((32 + g * 8) ^ sw)];
            f16x8 al0 = *(const f16x8*)&QJ[buf][1][row * 64 + ((g * 8) ^ sw)];
            f16x8 al1 = *(const f16x8*)&QJ[buf][1][row * 64 + ((32 + g * 8) ^ sw)];
            f32x4 s = {0.f, 0.f, 0.f, 0.f};
            s = MFMA_F16(ah0, qbh[0], s);
            s = MFMA_F16(ah1, qbh[1], s);
            s = MFMA_F16(ah0, qbl[0], s);
            s = MFMA_F16(ah1, qbl[1], s);
            s = MFMA_F16(al0, qbh[0], s);
            s = MFMA_F16(al1, qbh[1], s);
            sv[f] = s;
        }

        // ---- stage qj(jt+1) ds_writes (loads aged by S-phase)
#pragma unroll
        for (int pl = 0; pl < 2; ++pl)
#pragma unroll
            for (int t = 0; t < 2; ++t) {
                const int row = wv * 16 + t * 8 + rl;
                *(f16x8*)&QJ[buf ^ 1][pl][row * 64 + ((cb * 8) ^ (rl * 8))] = stg[pl * 2 + t];
            }

        // ---- phase 1c: online softmax (lane owns ONE i = wv*16+r16, 16 j-values)
        float m_t = sv[0][0];
#pragma unroll
        for (int f = 0; f < 4; ++f)
#pragma unroll
            for (int r = 0; r < 4; ++r) m_t = fmaxf(m_t, sv[f][r]);
        m_t = fmaxf(m_t, __shfl_xor(m_t, 16));
        m_t = fmaxf(m_t, __shfl_xor(m_t, 32));
        const float M_new = (m_t > M_run + 6.0f) ? m_t : M_run;
        const float fsc = __expf(M_run - M_new);
        float psum = 0.f;
#pragma unroll
        for (int f = 0; f < 4; ++f)
#pragma unroll
            for (int r = 0; r < 4; ++r) {
                float ev = __expf(sv[f][r] - M_new);
                sv[f][r] = ev;
                psum += ev;
            }
        psum += __shfl_xor(psum, 16);
        psum += __shfl_xor(psum, 32);
        l_run = l_run * fsc + psum;
        M_run = M_new;

        const int iP = wv * 16 + r16;
        const int swp = (iP & 7) * 8;
#pragma unroll
        for (int f = 0; f < 4; ++f) {
            f16x4 pv;
#pragma unroll
            for (int r = 0; r < 4; ++r) pv[r] = (half_t)sv[f][r];
            *(f16x4*)&P[buf][iP * 64 + ((f * 16 + g * 4) ^ swp)] = pv;
        }
        if (g == 0) FS[buf][iP] = fsc;

        __syncthreads();

        // ---- phase 2: PV (unnormalized accumulate) with rare rescale
        float fr[4];
#pragma unroll
        for (int fi = 0; fi < 4; ++fi) fr[fi] = FS[buf][fi * 16 + r16];
        if (!__all(fr[0] + fr[1] + fr[2] + fr[3] == 4.0f)) {
#pragma unroll
            for (int cf = 0; cf < 4; ++cf)
#pragma unroll
                for (int fi = 0; fi < 4; ++fi) acc[cf][fi] *= fr[fi];
        }
        __builtin_amdgcn_s_setprio(1);
#pragma unroll
        for (int ks = 0; ks < 2; ++ks) {
            f16x8 pf[4];
#pragma unroll
            for (int fi = 0; fi < 4; ++fi) {
                const int ip = fi * 16 + r16;
                pf[fi] = *(const f16x8*)&P[buf][ip * 64 + ((ks * 32 + g * 8) ^ ((ip & 7) * 8))];
            }
#pragma unroll
            for (int cf = 0; cf < 4; ++cf)
#pragma unroll
                for (int fi = 0; fi < 4; ++fi)
                    acc[cf][fi] = MFMA_F16(vfrag[cf][ks], pf[fi], acc[cf][fi]);
        }
        __builtin_amdgcn_s_setprio(0);
    }

    // ---- epilogue: share l across waves, normalize, blend, write
    if (g == 0) LS[wv * 16 + r16] = l_run;
    __syncthreads();
    float linv[4];
#pragma unroll
    for (int fi = 0; fi < 4; ++fi) linv[fi] = 1.0f / LS[fi * 16 + r16];

    const size_t outbase = ((size_t)n * 2 * CIN + (size_t)chunk * CIN) * HW;
#pragma unroll
    for (int fi = 0; fi < 4; ++fi) {
        const int i = i0 + fi * 16 + r16;
        float mk = 0.f;
        if (chunk == 0) mk = maskp[n * HW + i];
#pragma unroll
        for (int cf = 0; cf < 4; ++cf) {
#pragma unroll
            for (int r = 0; r < 4; ++r) {
                const int c = c0 + cf * 16 + g * 4 + r;
                float o = acc[cf][fi][r] * linv[fi];
                if (chunk == 0) {
                    const float rv = reff[((size_t)n * CIN + c) * HW + i];
                    o = (1.f - mk) * o + mk * rv;
                }
                out[outbase + (size_t)c * HW + i] = o;
            }
        }
    }
}

extern "C" void kernel_launch(void* const* d_in, const int* in_sizes, int n_in,
                              void* d_out, int out_size, void* d_ws, size_t ws_size,
                              hipStream_t stream) {
    const float* src_mask = (const float*)d_in[0];
    const float* src_feat = (const float*)d_in[1];
    const float* ref_feat = (const float*)d_in[2];
    const float* conv_w   = (const float*)d_in[3];
    float* out = (float*)d_out;

    char* ws = (char*)d_ws;
    const size_t qbytes = (size_t)NBATCH * HW * CQ * sizeof(half_t);          // 4 MB
    const size_t vbytes = (size_t)2 * NBATCH * CIN * HW * sizeof(half_t);     // 33.6 MB
    half_t* qth = (half_t*)ws;  ws += qbytes;
    half_t* qtl = (half_t*)ws;  ws += qbytes;
    half_t* vh  = (half_t*)ws;  ws += vbytes;

    k_prep<<<dim3(16384), dim3(256), 0, stream>>>(ref_feat, src_feat, vh);
    k_query<<<dim3(256), dim3(256), 0, stream>>>(src_feat, conv_w, qth, qtl);
    k_apply<<<dim3(1024), dim3(256), 0, stream>>>(qth, qtl, vh, ref_feat,
                                                  src_mask, out);
}